// Round 12
// baseline (1444.926 us; speedup 1.0000x reference)
//
#include <hip/hip_runtime.h>

typedef __attribute__((ext_vector_type(8))) _Float16 f16x8;
typedef __attribute__((ext_vector_type(4))) float     f32x4;
typedef __attribute__((ext_vector_type(4))) unsigned  u32x4;

#define L2E 1.44269504f

__device__ __forceinline__ unsigned pku(float a, float b) {
    return __builtin_bit_cast(unsigned, __builtin_amdgcn_cvt_pkrtz(a, b));
}
__device__ __forceinline__ float sig2(float s) {  // s pre-scaled by -log2e
    return __builtin_amdgcn_rcpf(1.0f + __builtin_amdgcn_exp2f(s));
}

// ================= ws layout (u32 words) =================
// State ordering: s = i*8 + u  (i = hidden 0..3, u = unit block: 0=hm, 1..7=hj[0..6])
// Gate-row ordering within unit block: m = i*4 + c, c in {0:r, 1:z, 2:gi_n, 3:gh_n}
// [0..2047]     A-frags:  ub*256 + lane*4 + w   f16-pair (k = L4*8+2w, +1) of row m=Ln
// [2048..2175]  C bias:   ub*16 + m  (f32)      (rz biases *-log2e, n biases *2log2e)
// [2176..2687]  init A:   b*256 + lane*4 + w    W_init rows: i=m/4, u=b*4+m%4; k = x index
// [2688..2719]  init C:   b*16 + m  (f32)
// [2720..2724]  Wact[0..3], bact

__global__ __launch_bounds__(256) void prep_kernel(
    const float* __restrict__ Wj,    const float* __restrict__ bj,
    const float* __restrict__ Wm,    const float* __restrict__ bm,
    const float* __restrict__ Wih_j, const float* __restrict__ Whh_j,
    const float* __restrict__ bih_j, const float* __restrict__ bhh_j,
    const float* __restrict__ Wih_m, const float* __restrict__ Whh_m,
    const float* __restrict__ bih_m, const float* __restrict__ bhh_m,
    const float* __restrict__ Wact,  const float* __restrict__ bact,
    unsigned* __restrict__ ws)
{
    int t = blockIdx.x * 256 + threadIdx.x;
    const float c1 = -L2E, c2 = 2.0f * L2E;
    if (t < 2048) {                       // main A-frags
        int ub = t >> 8, rr = t & 255, L = rr >> 2, w = rr & 3;
        int Ln = L & 15, L4 = L >> 4;
        int i = Ln >> 2, c = Ln & 3;
        float vv[2];
        #pragma unroll
        for (int e = 0; e < 2; ++e) {
            int k = L4 * 8 + 2 * w + e;
            int is = k >> 3, us = k & 7;
            float val = 0.0f;
            if (ub == 0) {                // m-unit: x = hj0 (block1), h = hm (block0)
                int g = (c == 0) ? i : (c == 1) ? 4 + i : 8 + i;
                if (c <= 1) {
                    if (us == 1) val += Wih_m[g*4 + is];
                    if (us == 0) val += Whh_m[g*4 + is];
                } else if (c == 2) {
                    if (us == 1) val += Wih_m[g*4 + is];
                } else {
                    if (us == 0) val += Whh_m[g*4 + is];
                }
            } else {                      // joint tj = ub-1
                int tj = ub - 1;
                int lb = (tj == 0) ? 0 : tj;        // left block (hm or hj[tj-1])
                int rb = (tj < 6) ? tj + 2 : -1;    // right block or none
                int g = (c == 0) ? i : (c == 1) ? 4 + i : 8 + i;
                if (c <= 1) {
                    if (us == lb) val += Wih_j[g*8 + is];
                    if (us == rb) val += Wih_j[g*8 + 4 + is];
                    if (us == ub) val += Whh_j[g*4 + is];
                } else if (c == 2) {
                    if (us == lb) val += Wih_j[g*8 + is];
                    if (us == rb) val += Wih_j[g*8 + 4 + is];
                } else {
                    if (us == ub) val += Whh_j[g*4 + is];
                }
            }
            vv[e] = val * ((c <= 1) ? c1 : c2);
        }
        ws[t] = pku(vv[0], vv[1]);
    } else if (t < 2176) {                // C biases
        int tt = t - 2048, ub = tt >> 4, m = tt & 15, i = m >> 2, c = m & 3;
        const float* bi = ub ? bih_j : bih_m;
        const float* bh = ub ? bhh_j : bhh_m;
        float val = (c == 0) ? (bi[i] + bh[i]) * c1
                  : (c == 1) ? (bi[4 + i] + bh[4 + i]) * c1
                  : (c == 2) ? bi[8 + i] * c2
                  :            bh[8 + i] * c2;
        ws[t] = __float_as_uint(val);
    } else if (t < 2688) {                // init A-frags
        int tt = t - 2176, b = tt >> 8, rr = tt & 255, L = rr >> 2, w = rr & 3;
        int Ln = L & 15, L4 = L >> 4;
        int i = Ln >> 2, q = Ln & 3, u = b * 4 + q;
        float vv[2];
        #pragma unroll
        for (int e = 0; e < 2; ++e) {
            int k = L4 * 8 + 2 * w + e;
            float val = 0.0f;
            if (k < 19) {
                if (u == 0) { if (k < 5) val = Wm[i*5 + k]; }
                else {
                    int tj = u - 1;
                    if (k == 5 + tj)       val = Wj[i*2 + 0];
                    else if (k == 12 + tj) val = Wj[i*2 + 1];
                }
            }
            vv[e] = val;
        }
        ws[t] = pku(vv[0], vv[1]);
    } else if (t < 2720) {                // init C
        int tt = t - 2688, b = tt >> 4, m = tt & 15, i = m >> 2, q = m & 3;
        int u = b * 4 + q;
        ws[t] = __float_as_uint(u == 0 ? bm[i] : bj[i]);
    } else if (t < 2724) {
        ws[t] = __float_as_uint(Wact[t - 2720]);
    } else if (t == 2724) {
        ws[t] = __float_as_uint(bact[0]);
    }
}

// r12: __launch_bounds__(256,6) — declare 6 waves/EU so the scheduler can
// co-resident ~24 waves/CU (was 3 -> Occupancy 33.5%). VGPR cap 85 vs the
// 84 the compiler already allocates: no spill risk, single-variable change.
__global__ __launch_bounds__(256, 6) void aggreg_kernel(
    const float* __restrict__ x, const unsigned* __restrict__ ws,
    float* __restrict__ out)
{
    const int lane = threadIdx.x & 63;
    const int Ln = lane & 15, L4 = lane >> 4;
    const int wave = blockIdx.x * 4 + (threadIdx.x >> 6);
    const long long rowbase = (long long)wave << 6;

    // ---- stage weight table (A-frags + C biases, 8.7 KB) into LDS ----
    __shared__ unsigned sh[2176];
    for (int i = threadIdx.x; i < 2176; i += 256) sh[i] = ws[i];
    __syncthreads();

    // ---- init: state = W_init @ x via 2 MFMAs per row-group ----
    f16x8 IA[2]; f32x4 IC[2];
    #pragma unroll
    for (int b = 0; b < 2; ++b) {
        u32x4 q = *(const u32x4*)(ws + 2176 + b * 256 + lane * 4);
        IA[b] = __builtin_bit_cast(f16x8, q);
        IC[b] = *(const f32x4*)((const float*)ws + 2688 + b * 16 + L4 * 4);
    }
    float h[4][8];          // h[group][unit] for (row = rowbase+g*16+Ln, hidden = L4)
    unsigned Bf[4][4];      // B-fragments (f16 pairs), lane-local repack of h
    #pragma unroll
    for (int g = 0; g < 4; ++g) {
        long long row = rowbase + g * 16 + Ln;
        const float* xp = x + row * 19;
        float xf[8];
        #pragma unroll
        for (int e = 0; e < 8; ++e) xf[e] = 0.0f;
        if (L4 < 2) {
            #pragma unroll
            for (int e = 0; e < 8; ++e) xf[e] = xp[L4 * 8 + e];
        } else if (L4 == 2) {
            xf[0] = xp[16]; xf[1] = xp[17]; xf[2] = xp[18];
        }
        u32x4 bq;
        bq[0] = pku(xf[0], xf[1]); bq[1] = pku(xf[2], xf[3]);
        bq[2] = pku(xf[4], xf[5]); bq[3] = pku(xf[6], xf[7]);
        f16x8 bxf = __builtin_bit_cast(f16x8, bq);
        f32x4 d0 = __builtin_amdgcn_mfma_f32_16x16x32_f16(IA[0], bxf, IC[0], 0, 0, 0);
        f32x4 d1 = __builtin_amdgcn_mfma_f32_16x16x32_f16(IA[1], bxf, IC[1], 0, 0, 0);
        #pragma unroll
        for (int r = 0; r < 4; ++r) { h[g][r] = d0[r]; h[g][4 + r] = d1[r]; }
        #pragma unroll
        for (int w = 0; w < 4; ++w) Bf[g][w] = pku(h[g][2*w], h[g][2*w+1]);
    }

    // ---- 7 Jacobi iterations: gates = W @ state (MFMA), EW lane-local ----
    for (int it = 0; it < 7; ++it) {
        #pragma unroll
        for (int g = 0; g < 4; ++g) {
            if (it > 0) {   // repack at iteration start (skips the dead final repack)
                #pragma unroll
                for (int w = 0; w < 4; ++w) Bf[g][w] = pku(h[g][2*w], h[g][2*w+1]);
            }
            u32x4 bq; bq[0] = Bf[g][0]; bq[1] = Bf[g][1]; bq[2] = Bf[g][2]; bq[3] = Bf[g][3];
            f16x8 bg = __builtin_bit_cast(f16x8, bq);
            #pragma unroll
            for (int u = 0; u < 8; ++u) {
                if (u == 0 && it == 6) continue;   // h_m dead after last iteration
                u32x4 aq = *(const u32x4*)(sh + u * 256 + lane * 4);
                f16x8 Au = __builtin_bit_cast(f16x8, aq);
                f32x4 Cu = *(const f32x4*)((const float*)sh + 2048 + u * 16 + L4 * 4);
                f32x4 d = __builtin_amdgcn_mfma_f32_16x16x32_f16(Au, bg, Cu, 0, 0, 0);
                // d[0]=r-pre(-l2e), d[1]=z-pre(-l2e), d[2]=gi_n(2l2e), d[3]=gh_n(2l2e)
                float r  = sig2(d[0]);
                float z  = sig2(d[1]);
                float v  = fmaf(r, d[3], d[2]);
                float nn = 1.0f - 2.0f * __builtin_amdgcn_rcpf(__builtin_amdgcn_exp2f(v) + 1.0f);
                h[g][u] = nn + z * (h[g][u] - nn);   // in-place ok: B stays old until repack
            }
        }
    }

    // ---- epilogue: acts = hj @ Wact.T + bact (butterfly reduce over hidden i) ----
    const float wact = ((const float*)ws)[2720 + L4];
    const float ba   = ((const float*)ws)[2724];
    #pragma unroll
    for (int g = 0; g < 4; ++g) {
        long long row = rowbase + g * 16 + Ln;
        #pragma unroll
        for (int u = 1; u < 8; ++u) {
            float v = wact * h[g][u];
            v += __shfl_xor(v, 16, 64);
            v += __shfl_xor(v, 32, 64);
            if (L4 == 0) out[row * 7 + (u - 1)] = v + ba;
        }
    }
}

extern "C" void kernel_launch(void* const* d_in, const int* in_sizes, int n_in,
                              void* d_out, int out_size, void* d_ws, size_t ws_size,
                              hipStream_t stream) {
    const float* x      = (const float*)d_in[0];
    const float* Wj     = (const float*)d_in[1];
    const float* bj     = (const float*)d_in[2];
    const float* Wm     = (const float*)d_in[3];
    const float* bm     = (const float*)d_in[4];
    const float* Wih_j  = (const float*)d_in[5];
    const float* Whh_j  = (const float*)d_in[6];
    const float* bih_j  = (const float*)d_in[7];
    const float* bhh_j  = (const float*)d_in[8];
    const float* Wih_m  = (const float*)d_in[9];
    const float* Whh_m  = (const float*)d_in[10];
    const float* bih_m  = (const float*)d_in[11];
    const float* bhh_m  = (const float*)d_in[12];
    const float* Wact   = (const float*)d_in[13];
    const float* bact   = (const float*)d_in[14];
    float* out = (float*)d_out;
    unsigned* ws = (unsigned*)d_ws;

    prep_kernel<<<11, 256, 0, stream>>>(Wj, bj, Wm, bm,
                                        Wih_j, Whh_j, bih_j, bhh_j,
                                        Wih_m, Whh_m, bih_m, bhh_m,
                                        Wact, bact, ws);

    int B = in_sizes[0] / 19;        // 2097152 rows, exact multiple of 256
    int grid = B / 256;              // 256 rows per block (4 waves x 64 rows)
    aggreg_kernel<<<grid, 256, 0, stream>>>(x, ws, out);
}

// Round 13
// 272.253 us; speedup vs baseline: 5.3073x; 5.3073x over previous
//
#include <hip/hip_runtime.h>

typedef __attribute__((ext_vector_type(8))) _Float16 f16x8;
typedef __attribute__((ext_vector_type(4))) float     f32x4;
typedef __attribute__((ext_vector_type(4))) unsigned  u32x4;

#define L2E 1.44269504f

__device__ __forceinline__ unsigned pku(float a, float b) {
    return __builtin_bit_cast(unsigned, __builtin_amdgcn_cvt_pkrtz(a, b));
}
__device__ __forceinline__ float sig2(float s) {  // s pre-scaled by -log2e
    return __builtin_amdgcn_rcpf(1.0f + __builtin_amdgcn_exp2f(s));
}

// ================= ws layout (u32 words) =================
// State ordering: s = i*8 + u  (i = hidden 0..3, u = unit block: 0=hm, 1..7=hj[0..6])
// Gate-row ordering within unit block: m = i*4 + c, c in {0:r, 1:z, 2:gi_n, 3:gh_n}
// [0..2047]     A-frags:  ub*256 + lane*4 + w   f16-pair (k = L4*8+2w, +1) of row m=Ln
// [2048..2175]  C bias:   ub*16 + m  (f32)      (rz biases *-log2e, n biases *2log2e)
// [2176..2687]  init A:   b*256 + lane*4 + w    W_init rows: i=m/4, u=b*4+m%4; k = x index
// [2688..2719]  init C:   b*16 + m  (f32)
// [2720..2724]  Wact[0..3], bact

__global__ __launch_bounds__(256) void prep_kernel(
    const float* __restrict__ Wj,    const float* __restrict__ bj,
    const float* __restrict__ Wm,    const float* __restrict__ bm,
    const float* __restrict__ Wih_j, const float* __restrict__ Whh_j,
    const float* __restrict__ bih_j, const float* __restrict__ bhh_j,
    const float* __restrict__ Wih_m, const float* __restrict__ Whh_m,
    const float* __restrict__ bih_m, const float* __restrict__ bhh_m,
    const float* __restrict__ Wact,  const float* __restrict__ bact,
    unsigned* __restrict__ ws)
{
    int t = blockIdx.x * 256 + threadIdx.x;
    const float c1 = -L2E, c2 = 2.0f * L2E;
    if (t < 2048) {                       // main A-frags
        int ub = t >> 8, rr = t & 255, L = rr >> 2, w = rr & 3;
        int Ln = L & 15, L4 = L >> 4;
        int i = Ln >> 2, c = Ln & 3;
        float vv[2];
        #pragma unroll
        for (int e = 0; e < 2; ++e) {
            int k = L4 * 8 + 2 * w + e;
            int is = k >> 3, us = k & 7;
            float val = 0.0f;
            if (ub == 0) {                // m-unit: x = hj0 (block1), h = hm (block0)
                int g = (c == 0) ? i : (c == 1) ? 4 + i : 8 + i;
                if (c <= 1) {
                    if (us == 1) val += Wih_m[g*4 + is];
                    if (us == 0) val += Whh_m[g*4 + is];
                } else if (c == 2) {
                    if (us == 1) val += Wih_m[g*4 + is];
                } else {
                    if (us == 0) val += Whh_m[g*4 + is];
                }
            } else {                      // joint tj = ub-1
                int tj = ub - 1;
                int lb = (tj == 0) ? 0 : tj;        // left block (hm or hj[tj-1])
                int rb = (tj < 6) ? tj + 2 : -1;    // right block or none
                int g = (c == 0) ? i : (c == 1) ? 4 + i : 8 + i;
                if (c <= 1) {
                    if (us == lb) val += Wih_j[g*8 + is];
                    if (us == rb) val += Wih_j[g*8 + 4 + is];
                    if (us == ub) val += Whh_j[g*4 + is];
                } else if (c == 2) {
                    if (us == lb) val += Wih_j[g*8 + is];
                    if (us == rb) val += Wih_j[g*8 + 4 + is];
                } else {
                    if (us == ub) val += Whh_j[g*4 + is];
                }
            }
            vv[e] = val * ((c <= 1) ? c1 : c2);
        }
        ws[t] = pku(vv[0], vv[1]);
    } else if (t < 2176) {                // C biases
        int tt = t - 2048, ub = tt >> 4, m = tt & 15, i = m >> 2, c = m & 3;
        const float* bi = ub ? bih_j : bih_m;
        const float* bh = ub ? bhh_j : bhh_m;
        float val = (c == 0) ? (bi[i] + bh[i]) * c1
                  : (c == 1) ? (bi[4 + i] + bh[4 + i]) * c1
                  : (c == 2) ? bi[8 + i] * c2
                  :            bh[8 + i] * c2;
        ws[t] = __float_as_uint(val);
    } else if (t < 2688) {                // init A-frags
        int tt = t - 2176, b = tt >> 8, rr = tt & 255, L = rr >> 2, w = rr & 3;
        int Ln = L & 15, L4 = L >> 4;
        int i = Ln >> 2, q = Ln & 3, u = b * 4 + q;
        float vv[2];
        #pragma unroll
        for (int e = 0; e < 2; ++e) {
            int k = L4 * 8 + 2 * w + e;
            float val = 0.0f;
            if (k < 19) {
                if (u == 0) { if (k < 5) val = Wm[i*5 + k]; }
                else {
                    int tj = u - 1;
                    if (k == 5 + tj)       val = Wj[i*2 + 0];
                    else if (k == 12 + tj) val = Wj[i*2 + 1];
                }
            }
            vv[e] = val;
        }
        ws[t] = pku(vv[0], vv[1]);
    } else if (t < 2720) {                // init C
        int tt = t - 2688, b = tt >> 4, m = tt & 15, i = m >> 2, q = m & 3;
        int u = b * 4 + q;
        ws[t] = __float_as_uint(u == 0 ? bm[i] : bj[i]);
    } else if (t < 2724) {
        ws[t] = __float_as_uint(Wact[t - 2720]);
    } else if (t == 2724) {
        ws[t] = __float_as_uint(bact[0]);
    }
}

// r13: u-outer / g-inner loop order — each A[u]/C[u] LDS read serves 4 MFMAs
// (was potentially 4x redundant inside the unrolled g-loop). launch_bounds
// back to (256,3): r12 showed tighter caps trigger catastrophic spilling
// (unified VGPR+AGPR budget ~148/wave is what actually caps occupancy at ~3/SIMD).
__global__ __launch_bounds__(256, 3) void aggreg_kernel(
    const float* __restrict__ x, const unsigned* __restrict__ ws,
    float* __restrict__ out)
{
    const int lane = threadIdx.x & 63;
    const int Ln = lane & 15, L4 = lane >> 4;
    const int wave = blockIdx.x * 4 + (threadIdx.x >> 6);
    const long long rowbase = (long long)wave << 6;

    // ---- stage weight table (A-frags + C biases, 8.7 KB) into LDS ----
    __shared__ unsigned sh[2176];
    for (int i = threadIdx.x; i < 2176; i += 256) sh[i] = ws[i];
    __syncthreads();

    // ---- init: state = W_init @ x via 2 MFMAs per row-group ----
    f16x8 IA[2]; f32x4 IC[2];
    #pragma unroll
    for (int b = 0; b < 2; ++b) {
        u32x4 q = *(const u32x4*)(ws + 2176 + b * 256 + lane * 4);
        IA[b] = __builtin_bit_cast(f16x8, q);
        IC[b] = *(const f32x4*)((const float*)ws + 2688 + b * 16 + L4 * 4);
    }
    float h[4][8];          // h[group][unit] for (row = rowbase+g*16+Ln, hidden = L4)
    f16x8 bg[4];            // packed state per group (B-fragment)
    #pragma unroll
    for (int g = 0; g < 4; ++g) {
        long long row = rowbase + g * 16 + Ln;
        const float* xp = x + row * 19;
        float xf[8];
        #pragma unroll
        for (int e = 0; e < 8; ++e) xf[e] = 0.0f;
        if (L4 < 2) {
            #pragma unroll
            for (int e = 0; e < 8; ++e) xf[e] = xp[L4 * 8 + e];
        } else if (L4 == 2) {
            xf[0] = xp[16]; xf[1] = xp[17]; xf[2] = xp[18];
        }
        u32x4 bq;
        bq[0] = pku(xf[0], xf[1]); bq[1] = pku(xf[2], xf[3]);
        bq[2] = pku(xf[4], xf[5]); bq[3] = pku(xf[6], xf[7]);
        f16x8 bxf = __builtin_bit_cast(f16x8, bq);
        f32x4 d0 = __builtin_amdgcn_mfma_f32_16x16x32_f16(IA[0], bxf, IC[0], 0, 0, 0);
        f32x4 d1 = __builtin_amdgcn_mfma_f32_16x16x32_f16(IA[1], bxf, IC[1], 0, 0, 0);
        #pragma unroll
        for (int r = 0; r < 4; ++r) { h[g][r] = d0[r]; h[g][4 + r] = d1[r]; }
        u32x4 pq;
        #pragma unroll
        for (int w = 0; w < 4; ++w) pq[w] = pku(h[g][2*w], h[g][2*w+1]);
        bg[g] = __builtin_bit_cast(f16x8, pq);
    }

    // ---- 7 Jacobi iterations: gates = W @ state (MFMA), EW lane-local ----
    for (int it = 0; it < 7; ++it) {
        if (it > 0) {   // repack ALL groups first (units read old state), skip dead final
            #pragma unroll
            for (int g = 0; g < 4; ++g) {
                u32x4 pq;
                #pragma unroll
                for (int w = 0; w < 4; ++w) pq[w] = pku(h[g][2*w], h[g][2*w+1]);
                bg[g] = __builtin_bit_cast(f16x8, pq);
            }
        }
        #pragma unroll
        for (int u = 0; u < 8; ++u) {
            if (u == 0 && it == 6) continue;   // h_m dead after last iteration
            u32x4 aq = *(const u32x4*)(sh + u * 256 + lane * 4);
            f16x8 Au = __builtin_bit_cast(f16x8, aq);
            f32x4 Cu = *(const f32x4*)((const float*)sh + 2048 + u * 16 + L4 * 4);
            #pragma unroll
            for (int g = 0; g < 4; ++g) {
                f32x4 d = __builtin_amdgcn_mfma_f32_16x16x32_f16(Au, bg[g], Cu, 0, 0, 0);
                // d[0]=r-pre(-l2e), d[1]=z-pre(-l2e), d[2]=gi_n(2l2e), d[3]=gh_n(2l2e)
                float r  = sig2(d[0]);
                float z  = sig2(d[1]);
                float v  = fmaf(r, d[3], d[2]);
                float nn = 1.0f - 2.0f * __builtin_amdgcn_rcpf(__builtin_amdgcn_exp2f(v) + 1.0f);
                h[g][u] = nn + z * (h[g][u] - nn);   // in-place ok: bg stays old until repack
            }
        }
    }

    // ---- epilogue: acts = hj @ Wact.T + bact (butterfly reduce over hidden i) ----
    const float wact = ((const float*)ws)[2720 + L4];
    const float ba   = ((const float*)ws)[2724];
    #pragma unroll
    for (int g = 0; g < 4; ++g) {
        long long row = rowbase + g * 16 + Ln;
        #pragma unroll
        for (int u = 1; u < 8; ++u) {
            float v = wact * h[g][u];
            v += __shfl_xor(v, 16, 64);
            v += __shfl_xor(v, 32, 64);
            if (L4 == 0) out[row * 7 + (u - 1)] = v + ba;
        }
    }
}

extern "C" void kernel_launch(void* const* d_in, const int* in_sizes, int n_in,
                              void* d_out, int out_size, void* d_ws, size_t ws_size,
                              hipStream_t stream) {
    const float* x      = (const float*)d_in[0];
    const float* Wj     = (const float*)d_in[1];
    const float* bj     = (const float*)d_in[2];
    const float* Wm     = (const float*)d_in[3];
    const float* bm     = (const float*)d_in[4];
    const float* Wih_j  = (const float*)d_in[5];
    const float* Whh_j  = (const float*)d_in[6];
    const float* bih_j  = (const float*)d_in[7];
    const float* bhh_j  = (const float*)d_in[8];
    const float* Wih_m  = (const float*)d_in[9];
    const float* Whh_m  = (const float*)d_in[10];
    const float* bih_m  = (const float*)d_in[11];
    const float* bhh_m  = (const float*)d_in[12];
    const float* Wact   = (const float*)d_in[13];
    const float* bact   = (const float*)d_in[14];
    float* out = (float*)d_out;
    unsigned* ws = (unsigned*)d_ws;

    prep_kernel<<<11, 256, 0, stream>>>(Wj, bj, Wm, bm,
                                        Wih_j, Whh_j, bih_j, bhh_j,
                                        Wih_m, Whh_m, bih_m, bhh_m,
                                        Wact, bact, ws);

    int B = in_sizes[0] / 19;        // 2097152 rows, exact multiple of 256
    int grid = B / 256;              // 256 rows per block (4 waves x 64 rows)
    aggreg_kernel<<<grid, 256, 0, stream>>>(x, ws, out);
}